// Round 5
// baseline (854.073 us; speedup 1.0000x reference)
//
#include <hip/hip_runtime.h>
#include <hip/hip_bf16.h>

#define N_NODES 100000
#define N_EDGES 1600000

// ---------------- CSR build ----------------

__global__ void zero_cnt_k(int* cnt, int n) {
    int i = blockIdx.x * 256 + threadIdx.x;
    if (i < n) cnt[i] = 0;
}

__global__ void hist_k(const int* __restrict__ ei, int* __restrict__ cnt, int E) {
    int e = blockIdx.x * 256 + threadIdx.x;
    if (e < E) atomicAdd(&cnt[ei[E + e]], 1);
}

// scan + dis/sx fused: reads cnt once, emits exclusive block-scan, dis, sx
__global__ void scan_cnt_k(const int* __restrict__ cnt, const int* __restrict__ x,
                           int* __restrict__ offs, int* __restrict__ bsum,
                           float* __restrict__ dis, float2* __restrict__ sx, int n) {
    __shared__ int buf[2][256];
    int t = threadIdx.x;
    int i = blockIdx.x * 256 + t;
    int v = (i < n) ? cnt[i] : 0;
    if (i < n) {
        float d = rsqrtf(1.0f + (float)v);   // deg includes self-loop
        dis[i] = d;
        sx[i] = make_float2(d, __int_as_float(x[i]));
    }
    int p = 0;
    buf[0][t] = v;
    __syncthreads();
    for (int off = 1; off < 256; off <<= 1) {
        int nv = buf[p][t];
        if (t >= off) nv += buf[p][t - off];
        buf[p ^ 1][t] = nv;
        p ^= 1;
        __syncthreads();
    }
    if (i < n) offs[i] = buf[p][t] - v;
    if (t == 255) bsum[blockIdx.x] = buf[p][t];
}

__global__ void scan_bsum_k(int* __restrict__ bsum, int nb) {
    __shared__ int buf[2][512];
    int t = threadIdx.x;
    int v = (t < nb) ? bsum[t] : 0;
    int p = 0;
    buf[0][t] = v;
    __syncthreads();
    for (int off = 1; off < 512; off <<= 1) {
        int nv = buf[p][t];
        if (t >= off) nv += buf[p][t - off];
        buf[p ^ 1][t] = nv;
        p ^= 1;
        __syncthreads();
    }
    if (t < nb) bsum[t] = buf[p][t] - v;
}

__global__ void scan_add_k(int* __restrict__ offs, int* __restrict__ cursor,
                           const int* __restrict__ bsum, int n, int total) {
    int i = blockIdx.x * 256 + threadIdx.x;
    if (i < n) {
        int o = offs[i] + bsum[blockIdx.x];
        offs[i] = o;
        cursor[i] = o;
    }
    if (i == 0) offs[n] = total;
}

// bucketed by dst: srcs[pos] = src, eid[pos] = edge id
__global__ void fill_csr_k(const int* __restrict__ ei, int* __restrict__ cursor,
                           int* __restrict__ srcs, int* __restrict__ eid, int E) {
    int e = blockIdx.x * 256 + threadIdx.x;
    if (e < E) {
        int s = ei[e];
        int d = ei[E + e];
        int pos = atomicAdd(&cursor[d], 1);
        srcs[pos] = s;
        eid[pos] = e;
    }
}

// ---------------- layer 0+1 fused via vocab table ----------------

// T0[v][c] = sum_k emb[v][k] * W0[k][c]
__global__ void t0_k(const float* __restrict__ emb, const float* __restrict__ W0,
                     float* __restrict__ T0) {
    int v = blockIdx.x;      // 16 blocks
    int c = threadIdx.x;     // 128 threads
    float acc = 0.f;
    for (int k = 0; k < 128; ++k) acc += emb[v * 128 + k] * W0[k * 128 + c];
    T0[v * 128 + c] = acc;
}

// h1[d] = relu( di * (cvec @ T0) + b0 ),  cvec[v] = sum_{s: x[s]=v} dis[s] (+ di for self)
__global__ __launch_bounds__(256) void vgather_k(const float2* __restrict__ sx,
                                                 const int* __restrict__ offs,
                                                 const int* __restrict__ srcs,
                                                 const float* __restrict__ dis,
                                                 const int* __restrict__ x,
                                                 const float* __restrict__ T0,
                                                 const float* __restrict__ b0,
                                                 float* __restrict__ h, int n) {
    __shared__ float t0s[16 * 128];
    __shared__ float cv[4][16];
    int t = threadIdx.x;
    #pragma unroll
    for (int i = 0; i < 8; ++i) t0s[t + i * 256] = T0[t + i * 256];
    if (t < 64) cv[t >> 4][t & 15] = 0.f;
    __syncthreads();

    int w = t >> 6, lane = t & 63;
    int node = blockIdx.x * 4 + w;            // grid exact: N/4 blocks
    float di = dis[node];
    int j0 = offs[node], j1 = offs[node + 1];
    for (int j = j0 + lane; j < j1; j += 64) {
        float2 v = sx[srcs[j]];                // {dis[s], x[s]}
        atomicAdd(&cv[w][__float_as_int(v.y)], v.x);
    }
    if (lane == 0) atomicAdd(&cv[w][x[node]], di);   // self loop
    __syncthreads();

    float2 acc = make_float2(0.f, 0.f);
    #pragma unroll
    for (int v = 0; v < 16; ++v) {
        float c = cv[w][v];
        float2 tv = *(const float2*)&t0s[v * 128 + lane * 2];
        acc.x += c * tv.x;
        acc.y += c * tv.y;
    }
    float2 bb = *(const float2*)&b0[lane * 2];
    float2 r = make_float2(fmaxf(di * acc.x + bb.x, 0.f),
                           fmaxf(di * acc.y + bb.y, 0.f));
    ((float2*)h)[(size_t)node * 64 + lane] = r;
}

// ---------------- node matmul (row-prescaled by dis) ----------------
// k-chunked: h from LDS via float4 (ds_read_b128, broadcast across lanes)

__global__ __launch_bounds__(256) void matmul128_k(const float* __restrict__ in,
                                                   const float* __restrict__ W,
                                                   float* __restrict__ out,
                                                   const float* __restrict__ scale,
                                                   int n) {
    __shared__ float hlds[64][132];           // 132: float4-aligned rows (528 B)
    int t = threadIdx.x;
    int row0 = blockIdx.x * 64;
    #pragma unroll
    for (int it = 0; it < 8; ++it) {
        int i4 = t + it * 256;
        int r = i4 >> 5, c4 = (i4 & 31) << 2;
        float4 v = make_float4(0.f, 0.f, 0.f, 0.f);
        int g = row0 + r;
        if (g < n) v = *(const float4*)&in[(size_t)g * 128 + c4];
        *(float4*)&hlds[r][c4] = v;
    }
    __syncthreads();
    int cg = t & 31, rg = t >> 5;
    int c0 = cg << 2;
    float acc[8][4];
    #pragma unroll
    for (int r = 0; r < 8; ++r)
        for (int j = 0; j < 4; ++j) acc[r][j] = 0.f;
    #pragma unroll 4
    for (int kc = 0; kc < 32; ++kc) {
        float4 w0 = *(const float4*)&W[(size_t)(4 * kc + 0) * 128 + c0];
        float4 w1 = *(const float4*)&W[(size_t)(4 * kc + 1) * 128 + c0];
        float4 w2 = *(const float4*)&W[(size_t)(4 * kc + 2) * 128 + c0];
        float4 w3 = *(const float4*)&W[(size_t)(4 * kc + 3) * 128 + c0];
        #pragma unroll
        for (int r = 0; r < 8; ++r) {
            float4 hv = *(const float4*)&hlds[rg * 8 + r][kc * 4];
            acc[r][0] += hv.x * w0.x + hv.y * w1.x + hv.z * w2.x + hv.w * w3.x;
            acc[r][1] += hv.x * w0.y + hv.y * w1.y + hv.z * w2.y + hv.w * w3.y;
            acc[r][2] += hv.x * w0.z + hv.y * w1.z + hv.z * w2.z + hv.w * w3.z;
            acc[r][3] += hv.x * w0.w + hv.y * w1.w + hv.z * w2.w + hv.w * w3.w;
        }
    }
    #pragma unroll
    for (int r = 0; r < 8; ++r) {
        int g = row0 + rg * 8 + r;
        if (g < n) {
            float sc = scale[g];
            float4 o = make_float4(acc[r][0] * sc, acc[r][1] * sc,
                                   acc[r][2] * sc, acc[r][3] * sc);
            *(float4*)&out[(size_t)g * 128 + c0] = o;
        }
    }
}

// dual matmul: outA = in @ WA, outB = in @ WB (one staging pass)
__global__ __launch_bounds__(256) void matmulAB_k(const float* __restrict__ in,
                                                  const float* __restrict__ WA,
                                                  const float* __restrict__ WB,
                                                  float* __restrict__ outA,
                                                  float* __restrict__ outB, int n) {
    __shared__ float hlds[64][132];
    int t = threadIdx.x;
    int row0 = blockIdx.x * 64;
    #pragma unroll
    for (int it = 0; it < 8; ++it) {
        int i4 = t + it * 256;
        int r = i4 >> 5, c4 = (i4 & 31) << 2;
        float4 v = make_float4(0.f, 0.f, 0.f, 0.f);
        int g = row0 + r;
        if (g < n) v = *(const float4*)&in[(size_t)g * 128 + c4];
        *(float4*)&hlds[r][c4] = v;
    }
    __syncthreads();
    int cg = t & 31, rg = t >> 5;
    int c0 = cg << 2;
    float accA[8][4], accB[8][4];
    #pragma unroll
    for (int r = 0; r < 8; ++r)
        for (int j = 0; j < 4; ++j) { accA[r][j] = 0.f; accB[r][j] = 0.f; }
    #pragma unroll 2
    for (int kc = 0; kc < 32; ++kc) {
        float4 wa0 = *(const float4*)&WA[(size_t)(4 * kc + 0) * 128 + c0];
        float4 wa1 = *(const float4*)&WA[(size_t)(4 * kc + 1) * 128 + c0];
        float4 wa2 = *(const float4*)&WA[(size_t)(4 * kc + 2) * 128 + c0];
        float4 wa3 = *(const float4*)&WA[(size_t)(4 * kc + 3) * 128 + c0];
        float4 wb0 = *(const float4*)&WB[(size_t)(4 * kc + 0) * 128 + c0];
        float4 wb1 = *(const float4*)&WB[(size_t)(4 * kc + 1) * 128 + c0];
        float4 wb2 = *(const float4*)&WB[(size_t)(4 * kc + 2) * 128 + c0];
        float4 wb3 = *(const float4*)&WB[(size_t)(4 * kc + 3) * 128 + c0];
        #pragma unroll
        for (int r = 0; r < 8; ++r) {
            float4 hv = *(const float4*)&hlds[rg * 8 + r][kc * 4];
            accA[r][0] += hv.x * wa0.x + hv.y * wa1.x + hv.z * wa2.x + hv.w * wa3.x;
            accA[r][1] += hv.x * wa0.y + hv.y * wa1.y + hv.z * wa2.y + hv.w * wa3.y;
            accA[r][2] += hv.x * wa0.z + hv.y * wa1.z + hv.z * wa2.z + hv.w * wa3.z;
            accA[r][3] += hv.x * wa0.w + hv.y * wa1.w + hv.z * wa2.w + hv.w * wa3.w;
            accB[r][0] += hv.x * wb0.x + hv.y * wb1.x + hv.z * wb2.x + hv.w * wb3.x;
            accB[r][1] += hv.x * wb0.y + hv.y * wb1.y + hv.z * wb2.y + hv.w * wb3.y;
            accB[r][2] += hv.x * wb0.z + hv.y * wb1.z + hv.z * wb2.z + hv.w * wb3.z;
            accB[r][3] += hv.x * wb0.w + hv.y * wb1.w + hv.z * wb2.w + hv.w * wb3.w;
        }
    }
    #pragma unroll
    for (int r = 0; r < 8; ++r) {
        int g = row0 + rg * 8 + r;
        if (g < n) {
            *(float4*)&outA[(size_t)g * 128 + c0] = *(float4*)&accA[r][0];
            *(float4*)&outB[(size_t)g * 128 + c0] = *(float4*)&accB[r][0];
        }
    }
}

// ---------------- GCN gather (layers 2,3), hW prescaled by dis[row] ----------------
// 8 groups x 8 lanes per wave; group g walks every 8th edge.
// h_out[d] = relu( di * (hW'[d] + sum_e hW'[s]) + b )
__global__ __launch_bounds__(256) void gcn_gather_k(const float* __restrict__ hW,
                                                    const int* __restrict__ offs,
                                                    const int* __restrict__ srcs,
                                                    const float* __restrict__ dis,
                                                    const float* __restrict__ bias,
                                                    float* __restrict__ hout, int n) {
    int t = threadIdx.x;
    int node = blockIdx.x * 4 + (t >> 6);     // grid exact: N/4
    int lane = t & 63;
    int g = lane >> 3, sl = lane & 7;
    const float4* hw4 = (const float4*)hW;    // 32 float4 per row
    size_t selfrb = (size_t)node * 32 + sl;
    float4 a[4];
    if (g == 0) {                             // self term
        #pragma unroll
        for (int k = 0; k < 4; ++k) a[k] = hw4[selfrb + 8 * k];
    } else {
        #pragma unroll
        for (int k = 0; k < 4; ++k) a[k] = make_float4(0.f, 0.f, 0.f, 0.f);
    }
    int j0 = offs[node], j1 = offs[node + 1];
    for (int j = j0 + g; j < j1; j += 8) {
        size_t rb = (size_t)srcs[j] * 32 + sl;
        #pragma unroll
        for (int k = 0; k < 4; ++k) {
            float4 u = hw4[rb + 8 * k];
            a[k].x += u.x; a[k].y += u.y; a[k].z += u.z; a[k].w += u.w;
        }
    }
    #pragma unroll
    for (int m = 8; m <= 32; m <<= 1) {
        #pragma unroll
        for (int k = 0; k < 4; ++k) {
            a[k].x += __shfl_xor(a[k].x, m);
            a[k].y += __shfl_xor(a[k].y, m);
            a[k].z += __shfl_xor(a[k].z, m);
            a[k].w += __shfl_xor(a[k].w, m);
        }
    }
    if (g == 0) {
        float di = dis[node];
        #pragma unroll
        for (int k = 0; k < 4; ++k) {
            float4 bb = ((const float4*)bias)[sl + 8 * k];
            float4 r = make_float4(fmaxf(di * a[k].x + bb.x, 0.f),
                                   fmaxf(di * a[k].y + bb.y, 0.f),
                                   fmaxf(di * a[k].z + bb.z, 0.f),
                                   fmaxf(di * a[k].w + bb.w, 0.f));
            ((float4*)hout)[selfrb + 8 * k] = r;
        }
    }
}

// ---------------- edge MLP: CSR by dst, 4 edges x 16 lanes per wave ----------------
// (round-3 proven form: VGPR ~32, occupancy ~77%)
__global__ __launch_bounds__(256) void edge_mlp_k(const int* __restrict__ offs,
                                                  const int* __restrict__ srcs,
                                                  const int* __restrict__ eid,
                                                  const float* __restrict__ A,
                                                  const float* __restrict__ B,
                                                  const float* __restrict__ Wm2,
                                                  const float* __restrict__ bm1,
                                                  const float* __restrict__ bm2,
                                                  float* __restrict__ out, int n) {
    int t = threadIdx.x;
    int node = blockIdx.x * 4 + (t >> 6);
    int lane = t & 63;
    int g = lane >> 4, sl = lane & 15;
    int j0 = offs[node], j1 = offs[node + 1];
    if (j0 == j1) return;

    // pre = B[node][sl*8 .. +8] + bm1
    const float4* B4 = (const float4*)(B + (size_t)node * 128 + sl * 8);
    const float4* bm14 = (const float4*)(bm1 + sl * 8);
    float4 pre0 = B4[0], pre1 = B4[1];
    float4 m0 = bm14[0], m1 = bm14[1];
    pre0.x += m0.x; pre0.y += m0.y; pre0.z += m0.z; pre0.w += m0.w;
    pre1.x += m1.x; pre1.y += m1.y; pre1.z += m1.z; pre1.w += m1.w;

    float wv[8][3];
    #pragma unroll
    for (int i = 0; i < 8; ++i) {
        int f = sl * 8 + i;
        wv[i][0] = Wm2[f * 3 + 0];
        wv[i][1] = Wm2[f * 3 + 1];
        wv[i][2] = Wm2[f * 3 + 2];
    }
    float c0 = bm2[0], c1 = bm2[1], c2 = bm2[2];

    for (int jb = j0; jb < j1; jb += 4) {
        int jj = jb + g;
        bool act = jj < j1;
        int jsafe = act ? jj : j0;
        int s = srcs[jsafe];
        int e = eid[jsafe];
        const float4* A4 = (const float4*)(A + (size_t)s * 128 + sl * 8);
        float4 a0 = A4[0], a1 = A4[1];
        float h[8];
        h[0] = fmaxf(a0.x + pre0.x, 0.f);
        h[1] = fmaxf(a0.y + pre0.y, 0.f);
        h[2] = fmaxf(a0.z + pre0.z, 0.f);
        h[3] = fmaxf(a0.w + pre0.w, 0.f);
        h[4] = fmaxf(a1.x + pre1.x, 0.f);
        h[5] = fmaxf(a1.y + pre1.y, 0.f);
        h[6] = fmaxf(a1.z + pre1.z, 0.f);
        h[7] = fmaxf(a1.w + pre1.w, 0.f);
        float p0 = 0.f, p1 = 0.f, p2 = 0.f;
        #pragma unroll
        for (int i = 0; i < 8; ++i) {
            p0 += h[i] * wv[i][0];
            p1 += h[i] * wv[i][1];
            p2 += h[i] * wv[i][2];
        }
        #pragma unroll
        for (int m = 1; m <= 8; m <<= 1) {
            p0 += __shfl_xor(p0, m);
            p1 += __shfl_xor(p1, m);
            p2 += __shfl_xor(p2, m);
        }
        if (act && sl == 0) {
            out[(size_t)e * 3 + 0] = p0 + c0;
            out[(size_t)e * 3 + 1] = p1 + c1;
            out[(size_t)e * 3 + 2] = p2 + c2;
        }
    }
}

extern "C" void kernel_launch(void* const* d_in, const int* in_sizes, int n_in,
                              void* d_out, int out_size, void* d_ws, size_t ws_size,
                              hipStream_t stream) {
    const int N = N_NODES, E = N_EDGES;
    const int* x    = (const int*)d_in[0];
    const int* ei   = (const int*)d_in[1];
    const float* emb = (const float*)d_in[2];
    const float* W0 = (const float*)d_in[3];
    const float* b0 = (const float*)d_in[4];
    const float* W1 = (const float*)d_in[5];
    const float* b1 = (const float*)d_in[6];
    const float* W2 = (const float*)d_in[7];
    const float* b2 = (const float*)d_in[8];
    const float* Wm1 = (const float*)d_in[9];
    const float* bm1 = (const float*)d_in[10];
    const float* Wm2 = (const float*)d_in[11];
    const float* bm2 = (const float*)d_in[12];
    float* out = (float*)d_out;

    char* p = (char*)d_ws;
    auto alloc = [&](size_t bytes) {
        char* r = p;
        p += (bytes + 511) & ~(size_t)511;
        return r;
    };
    int*    cnt    = (int*)alloc((size_t)N * 4);
    float*  dis    = (float*)alloc((size_t)N * 4);
    float2* sx     = (float2*)alloc((size_t)N * 8);
    int*    offs   = (int*)alloc((size_t)(N + 1) * 4);
    int*    cursor = (int*)alloc((size_t)N * 4);
    int*    bsum   = (int*)alloc(512 * 4);
    int*    srcs   = (int*)alloc((size_t)E * 4);
    int*    eid    = (int*)alloc((size_t)E * 4);
    float*  T0     = (float*)alloc(16 * 128 * 4);
    float*  buf0   = (float*)alloc((size_t)N * 128 * 4);
    float*  buf1   = (float*)alloc((size_t)N * 128 * 4);
    float*  buf2   = (float*)alloc((size_t)N * 128 * 4);

    int nbN = (N + 255) / 256;
    int nbE = (E + 255) / 256;
    int nodeBlocks = N / 4;               // N divisible by 4
    int mmBlocks = (N + 63) / 64;

    zero_cnt_k<<<nbN, 256, 0, stream>>>(cnt, N);
    hist_k<<<nbE, 256, 0, stream>>>(ei, cnt, E);
    scan_cnt_k<<<nbN, 256, 0, stream>>>(cnt, x, offs, bsum, dis, sx, N);
    scan_bsum_k<<<1, 512, 0, stream>>>(bsum, nbN);
    scan_add_k<<<nbN, 256, 0, stream>>>(offs, cursor, bsum, N, E);
    fill_csr_k<<<nbE, 256, 0, stream>>>(ei, cursor, srcs, eid, E);

    t0_k<<<16, 128, 0, stream>>>(emb, W0, T0);
    vgather_k<<<nodeBlocks, 256, 0, stream>>>(sx, offs, srcs, dis, x, T0, b0, buf0, N);

    const float* Ws[2] = {W1, W2};
    const float* bs[2] = {b1, b2};
    for (int l = 0; l < 2; ++l) {
        matmul128_k<<<mmBlocks, 256, 0, stream>>>(buf0, Ws[l], buf1, dis, N);
        gcn_gather_k<<<nodeBlocks, 256, 0, stream>>>(buf1, offs, srcs, dis, bs[l], buf0, N);
    }

    matmulAB_k<<<mmBlocks, 256, 0, stream>>>(buf0, Wm1, Wm1 + 128 * 128, buf1, buf2, N);

    edge_mlp_k<<<nodeBlocks, 256, 0, stream>>>(offs, srcs, eid, buf1, buf2, Wm2, bm1, bm2, out, N);
}

// Round 6
// 812.633 us; speedup vs baseline: 1.0510x; 1.0510x over previous
//
#include <hip/hip_runtime.h>
#include <hip/hip_bf16.h>

#define N_NODES 100000
#define N_EDGES 1600000

// ---------------- CSR build ----------------

__global__ void hist_k(const int* __restrict__ ei, int* __restrict__ cnt, int E) {
    int e = blockIdx.x * 256 + threadIdx.x;
    if (e < E) atomicAdd(&cnt[ei[E + e]], 1);
}

// scan + dis/sxp fused: reads cnt once, emits exclusive block-scan, dis, packed sxp
// sxp[i] = bits of dis[i] with low 4 mantissa bits holding x[i] (rel err <= 1.8e-6)
__global__ void scan_cnt_k(const int* __restrict__ cnt, const int* __restrict__ x,
                           int* __restrict__ offs, int* __restrict__ bsum,
                           float* __restrict__ dis, int* __restrict__ sxp, int n) {
    __shared__ int buf[2][256];
    int t = threadIdx.x;
    int i = blockIdx.x * 256 + t;
    int v = (i < n) ? cnt[i] : 0;
    if (i < n) {
        float d = rsqrtf(1.0f + (float)v);   // deg includes self-loop
        dis[i] = d;
        sxp[i] = (__float_as_int(d) & ~15) | x[i];
    }
    int p = 0;
    buf[0][t] = v;
    __syncthreads();
    for (int off = 1; off < 256; off <<= 1) {
        int nv = buf[p][t];
        if (t >= off) nv += buf[p][t - off];
        buf[p ^ 1][t] = nv;
        p ^= 1;
        __syncthreads();
    }
    if (i < n) offs[i] = buf[p][t] - v;
    if (t == 255) bsum[blockIdx.x] = buf[p][t];
}

__global__ void scan_bsum_k(int* __restrict__ bsum, int nb) {
    __shared__ int buf[2][512];
    int t = threadIdx.x;
    int v = (t < nb) ? bsum[t] : 0;
    int p = 0;
    buf[0][t] = v;
    __syncthreads();
    for (int off = 1; off < 512; off <<= 1) {
        int nv = buf[p][t];
        if (t >= off) nv += buf[p][t - off];
        buf[p ^ 1][t] = nv;
        p ^= 1;
        __syncthreads();
    }
    if (t < nb) bsum[t] = buf[p][t] - v;
}

__global__ void scan_add_k(int* __restrict__ offs, int* __restrict__ cursor,
                           const int* __restrict__ bsum, int n, int total) {
    int i = blockIdx.x * 256 + threadIdx.x;
    if (i < n) {
        int o = offs[i] + bsum[blockIdx.x];
        offs[i] = o;
        cursor[i] = o;
    }
    if (i == 0) offs[n] = total;
}

// bucketed by dst: srcs[pos] = src, eid[pos] = edge id
__global__ void fill_csr_k(const int* __restrict__ ei, int* __restrict__ cursor,
                           int* __restrict__ srcs, int* __restrict__ eid, int E) {
    int e = blockIdx.x * 256 + threadIdx.x;
    if (e < E) {
        int s = ei[e];
        int d = ei[E + e];
        int pos = atomicAdd(&cursor[d], 1);
        srcs[pos] = s;
        eid[pos] = e;
    }
}

// ---------------- layer 0+1 fused via vocab table ----------------

// T0[v][c] = sum_k emb[v][k] * W0[k][c]
__global__ void t0_k(const float* __restrict__ emb, const float* __restrict__ W0,
                     float* __restrict__ T0) {
    int v = blockIdx.x;      // 16 blocks
    int c = threadIdx.x;     // 128 threads
    float acc = 0.f;
    for (int k = 0; k < 128; ++k) acc += emb[v * 128 + k] * W0[k * 128 + c];
    T0[v * 128 + c] = acc;
}

// h1[d] = relu( di * (cvec @ T0) + b0 ),  cvec[v] = sum_{s: x[s]=v} dis[s] (+ di for self)
__global__ __launch_bounds__(256) void vgather_k(const int* __restrict__ sxp,
                                                 const int* __restrict__ offs,
                                                 const int* __restrict__ srcs,
                                                 const float* __restrict__ dis,
                                                 const float* __restrict__ T0,
                                                 const float* __restrict__ b0,
                                                 float* __restrict__ h, int n) {
    __shared__ float t0s[16 * 128];
    __shared__ float cv[4][16];
    int t = threadIdx.x;
    #pragma unroll
    for (int i = 0; i < 8; ++i) t0s[t + i * 256] = T0[t + i * 256];
    if (t < 64) cv[t >> 4][t & 15] = 0.f;
    __syncthreads();

    int w = t >> 6, lane = t & 63;
    int node = blockIdx.x * 4 + w;            // grid exact: N/4 blocks
    float di = dis[node];
    int j0 = offs[node], j1 = offs[node + 1];
    for (int j = j0 + lane; j < j1; j += 64) {
        int b = sxp[srcs[j]];                  // packed {dis[s], x[s]}
        atomicAdd(&cv[w][b & 15], __int_as_float(b));
    }
    if (lane == 0) atomicAdd(&cv[w][sxp[node] & 15], di);   // self loop
    __syncthreads();

    float2 acc = make_float2(0.f, 0.f);
    #pragma unroll
    for (int v = 0; v < 16; ++v) {
        float c = cv[w][v];
        float2 tv = *(const float2*)&t0s[v * 128 + lane * 2];
        acc.x += c * tv.x;
        acc.y += c * tv.y;
    }
    float2 bb = *(const float2*)&b0[lane * 2];
    float2 r = make_float2(fmaxf(di * acc.x + bb.x, 0.f),
                           fmaxf(di * acc.y + bb.y, 0.f));
    ((float2*)h)[(size_t)node * 64 + lane] = r;
}

// ---------------- node matmul (row-prescaled by dis) — round-3 proven form ----------------

__global__ __launch_bounds__(256) void matmul128_k(const float* __restrict__ in,
                                                   const float* __restrict__ W,
                                                   float* __restrict__ out,
                                                   const float* __restrict__ scale,
                                                   int n) {
    __shared__ float hlds[64][132];
    int t = threadIdx.x;
    int row0 = blockIdx.x * 64;
    #pragma unroll
    for (int it = 0; it < 8; ++it) {
        int i4 = t + it * 256;
        int r = i4 >> 5, c4 = (i4 & 31) << 2;
        float4 v = make_float4(0.f, 0.f, 0.f, 0.f);
        int g = row0 + r;
        if (g < n) v = *(const float4*)&in[(size_t)g * 128 + c4];
        *(float4*)&hlds[r][c4] = v;
    }
    __syncthreads();
    int cg = t & 31, rg = t >> 5;
    int c0 = cg << 2;
    float acc[8][4];
    #pragma unroll
    for (int r = 0; r < 8; ++r)
        for (int j = 0; j < 4; ++j) acc[r][j] = 0.f;
    #pragma unroll 4
    for (int k = 0; k < 128; ++k) {
        float4 w = *(const float4*)&W[(size_t)k * 128 + c0];
        #pragma unroll
        for (int r = 0; r < 8; ++r) {
            float hk = hlds[rg * 8 + r][k];
            acc[r][0] += hk * w.x;
            acc[r][1] += hk * w.y;
            acc[r][2] += hk * w.z;
            acc[r][3] += hk * w.w;
        }
    }
    #pragma unroll
    for (int r = 0; r < 8; ++r) {
        int g = row0 + rg * 8 + r;
        if (g < n) {
            float sc = scale[g];
            float4 o = make_float4(acc[r][0] * sc, acc[r][1] * sc,
                                   acc[r][2] * sc, acc[r][3] * sc);
            *(float4*)&out[(size_t)g * 128 + c0] = o;
        }
    }
}

// dual matmul: outA = in @ WA, outB = in @ WB (one staging pass) — round-3 proven form
__global__ __launch_bounds__(256) void matmulAB_k(const float* __restrict__ in,
                                                  const float* __restrict__ WA,
                                                  const float* __restrict__ WB,
                                                  float* __restrict__ outA,
                                                  float* __restrict__ outB, int n) {
    __shared__ float hlds[64][132];
    int t = threadIdx.x;
    int row0 = blockIdx.x * 64;
    #pragma unroll
    for (int it = 0; it < 8; ++it) {
        int i4 = t + it * 256;
        int r = i4 >> 5, c4 = (i4 & 31) << 2;
        float4 v = make_float4(0.f, 0.f, 0.f, 0.f);
        int g = row0 + r;
        if (g < n) v = *(const float4*)&in[(size_t)g * 128 + c4];
        *(float4*)&hlds[r][c4] = v;
    }
    __syncthreads();
    int cg = t & 31, rg = t >> 5;
    int c0 = cg << 2;
    float accA[8][4], accB[8][4];
    #pragma unroll
    for (int r = 0; r < 8; ++r)
        for (int j = 0; j < 4; ++j) { accA[r][j] = 0.f; accB[r][j] = 0.f; }
    #pragma unroll 2
    for (int k = 0; k < 128; ++k) {
        float4 wa = *(const float4*)&WA[(size_t)k * 128 + c0];
        float4 wb = *(const float4*)&WB[(size_t)k * 128 + c0];
        #pragma unroll
        for (int r = 0; r < 8; ++r) {
            float hk = hlds[rg * 8 + r][k];
            accA[r][0] += hk * wa.x;
            accA[r][1] += hk * wa.y;
            accA[r][2] += hk * wa.z;
            accA[r][3] += hk * wa.w;
            accB[r][0] += hk * wb.x;
            accB[r][1] += hk * wb.y;
            accB[r][2] += hk * wb.z;
            accB[r][3] += hk * wb.w;
        }
    }
    #pragma unroll
    for (int r = 0; r < 8; ++r) {
        int g = row0 + rg * 8 + r;
        if (g < n) {
            *(float4*)&outA[(size_t)g * 128 + c0] = *(float4*)&accA[r][0];
            *(float4*)&outB[(size_t)g * 128 + c0] = *(float4*)&accB[r][0];
        }
    }
}

// ---------------- GCN gather (layers 2,3), hW prescaled by dis[row] ----------------
// 8 groups x 8 lanes per wave; group g walks every 8th edge.
// h_out[d] = relu( di * (hW'[d] + sum_e hW'[s]) + b )
__global__ __launch_bounds__(256) void gcn_gather_k(const float* __restrict__ hW,
                                                    const int* __restrict__ offs,
                                                    const int* __restrict__ srcs,
                                                    const float* __restrict__ dis,
                                                    const float* __restrict__ bias,
                                                    float* __restrict__ hout, int n) {
    int t = threadIdx.x;
    int node = blockIdx.x * 4 + (t >> 6);     // grid exact: N/4
    int lane = t & 63;
    int g = lane >> 3, sl = lane & 7;
    const float4* hw4 = (const float4*)hW;    // 32 float4 per row
    size_t selfrb = (size_t)node * 32 + sl;
    float4 a[4];
    if (g == 0) {                             // self term
        #pragma unroll
        for (int k = 0; k < 4; ++k) a[k] = hw4[selfrb + 8 * k];
    } else {
        #pragma unroll
        for (int k = 0; k < 4; ++k) a[k] = make_float4(0.f, 0.f, 0.f, 0.f);
    }
    int j0 = offs[node], j1 = offs[node + 1];
    for (int j = j0 + g; j < j1; j += 8) {
        size_t rb = (size_t)srcs[j] * 32 + sl;
        #pragma unroll
        for (int k = 0; k < 4; ++k) {
            float4 u = hw4[rb + 8 * k];
            a[k].x += u.x; a[k].y += u.y; a[k].z += u.z; a[k].w += u.w;
        }
    }
    #pragma unroll
    for (int m = 8; m <= 32; m <<= 1) {
        #pragma unroll
        for (int k = 0; k < 4; ++k) {
            a[k].x += __shfl_xor(a[k].x, m);
            a[k].y += __shfl_xor(a[k].y, m);
            a[k].z += __shfl_xor(a[k].z, m);
            a[k].w += __shfl_xor(a[k].w, m);
        }
    }
    if (g == 0) {
        float di = dis[node];
        #pragma unroll
        for (int k = 0; k < 4; ++k) {
            float4 bb = ((const float4*)bias)[sl + 8 * k];
            float4 r = make_float4(fmaxf(di * a[k].x + bb.x, 0.f),
                                   fmaxf(di * a[k].y + bb.y, 0.f),
                                   fmaxf(di * a[k].z + bb.z, 0.f),
                                   fmaxf(di * a[k].w + bb.w, 0.f));
            ((float4*)hout)[selfrb + 8 * k] = r;
        }
    }
}

// ---------------- edge MLP: CSR by dst, 4 edges x 16 lanes per wave ----------------
// (round-3 proven form: VGPR ~32, occupancy ~77%)
__global__ __launch_bounds__(256) void edge_mlp_k(const int* __restrict__ offs,
                                                  const int* __restrict__ srcs,
                                                  const int* __restrict__ eid,
                                                  const float* __restrict__ A,
                                                  const float* __restrict__ B,
                                                  const float* __restrict__ Wm2,
                                                  const float* __restrict__ bm1,
                                                  const float* __restrict__ bm2,
                                                  float* __restrict__ out, int n) {
    int t = threadIdx.x;
    int node = blockIdx.x * 4 + (t >> 6);
    int lane = t & 63;
    int g = lane >> 4, sl = lane & 15;
    int j0 = offs[node], j1 = offs[node + 1];
    if (j0 == j1) return;

    // pre = B[node][sl*8 .. +8] + bm1
    const float4* B4 = (const float4*)(B + (size_t)node * 128 + sl * 8);
    const float4* bm14 = (const float4*)(bm1 + sl * 8);
    float4 pre0 = B4[0], pre1 = B4[1];
    float4 m0 = bm14[0], m1 = bm14[1];
    pre0.x += m0.x; pre0.y += m0.y; pre0.z += m0.z; pre0.w += m0.w;
    pre1.x += m1.x; pre1.y += m1.y; pre1.z += m1.z; pre1.w += m1.w;

    float wv[8][3];
    #pragma unroll
    for (int i = 0; i < 8; ++i) {
        int f = sl * 8 + i;
        wv[i][0] = Wm2[f * 3 + 0];
        wv[i][1] = Wm2[f * 3 + 1];
        wv[i][2] = Wm2[f * 3 + 2];
    }
    float c0 = bm2[0], c1 = bm2[1], c2 = bm2[2];

    for (int jb = j0; jb < j1; jb += 4) {
        int jj = jb + g;
        bool act = jj < j1;
        int jsafe = act ? jj : j0;
        int s = srcs[jsafe];
        int e = eid[jsafe];
        const float4* A4 = (const float4*)(A + (size_t)s * 128 + sl * 8);
        float4 a0 = A4[0], a1 = A4[1];
        float h[8];
        h[0] = fmaxf(a0.x + pre0.x, 0.f);
        h[1] = fmaxf(a0.y + pre0.y, 0.f);
        h[2] = fmaxf(a0.z + pre0.z, 0.f);
        h[3] = fmaxf(a0.w + pre0.w, 0.f);
        h[4] = fmaxf(a1.x + pre1.x, 0.f);
        h[5] = fmaxf(a1.y + pre1.y, 0.f);
        h[6] = fmaxf(a1.z + pre1.z, 0.f);
        h[7] = fmaxf(a1.w + pre1.w, 0.f);
        float p0 = 0.f, p1 = 0.f, p2 = 0.f;
        #pragma unroll
        for (int i = 0; i < 8; ++i) {
            p0 += h[i] * wv[i][0];
            p1 += h[i] * wv[i][1];
            p2 += h[i] * wv[i][2];
        }
        #pragma unroll
        for (int m = 1; m <= 8; m <<= 1) {
            p0 += __shfl_xor(p0, m);
            p1 += __shfl_xor(p1, m);
            p2 += __shfl_xor(p2, m);
        }
        if (act && sl == 0) {
            out[(size_t)e * 3 + 0] = p0 + c0;
            out[(size_t)e * 3 + 1] = p1 + c1;
            out[(size_t)e * 3 + 2] = p2 + c2;
        }
    }
}

extern "C" void kernel_launch(void* const* d_in, const int* in_sizes, int n_in,
                              void* d_out, int out_size, void* d_ws, size_t ws_size,
                              hipStream_t stream) {
    const int N = N_NODES, E = N_EDGES;
    const int* x    = (const int*)d_in[0];
    const int* ei   = (const int*)d_in[1];
    const float* emb = (const float*)d_in[2];
    const float* W0 = (const float*)d_in[3];
    const float* b0 = (const float*)d_in[4];
    const float* W1 = (const float*)d_in[5];
    const float* b1 = (const float*)d_in[6];
    const float* W2 = (const float*)d_in[7];
    const float* b2 = (const float*)d_in[8];
    const float* Wm1 = (const float*)d_in[9];
    const float* bm1 = (const float*)d_in[10];
    const float* Wm2 = (const float*)d_in[11];
    const float* bm2 = (const float*)d_in[12];
    float* out = (float*)d_out;

    char* p = (char*)d_ws;
    auto alloc = [&](size_t bytes) {
        char* r = p;
        p += (bytes + 511) & ~(size_t)511;
        return r;
    };
    int*    cnt    = (int*)alloc((size_t)N * 4);
    float*  dis    = (float*)alloc((size_t)N * 4);
    int*    sxp    = (int*)alloc((size_t)N * 4);
    int*    offs   = (int*)alloc((size_t)(N + 1) * 4);
    int*    cursor = (int*)alloc((size_t)N * 4);
    int*    bsum   = (int*)alloc(512 * 4);
    int*    srcs   = (int*)alloc((size_t)E * 4);
    int*    eid    = (int*)alloc((size_t)E * 4);
    float*  T0     = (float*)alloc(16 * 128 * 4);
    float*  buf0   = (float*)alloc((size_t)N * 128 * 4);
    float*  buf1   = (float*)alloc((size_t)N * 128 * 4);
    float*  buf2   = (float*)alloc((size_t)N * 128 * 4);

    int nbN = (N + 255) / 256;
    int nbE = (E + 255) / 256;
    int nodeBlocks = N / 4;               // N divisible by 4
    int mmBlocks = (N + 63) / 64;

    hipMemsetAsync(cnt, 0, (size_t)N * 4, stream);
    hist_k<<<nbE, 256, 0, stream>>>(ei, cnt, E);
    scan_cnt_k<<<nbN, 256, 0, stream>>>(cnt, x, offs, bsum, dis, sxp, N);
    scan_bsum_k<<<1, 512, 0, stream>>>(bsum, nbN);
    scan_add_k<<<nbN, 256, 0, stream>>>(offs, cursor, bsum, N, E);
    fill_csr_k<<<nbE, 256, 0, stream>>>(ei, cursor, srcs, eid, E);

    t0_k<<<16, 128, 0, stream>>>(emb, W0, T0);
    vgather_k<<<nodeBlocks, 256, 0, stream>>>(sxp, offs, srcs, dis, T0, b0, buf0, N);

    const float* Ws[2] = {W1, W2};
    const float* bs[2] = {b1, b2};
    for (int l = 0; l < 2; ++l) {
        matmul128_k<<<mmBlocks, 256, 0, stream>>>(buf0, Ws[l], buf1, dis, N);
        gcn_gather_k<<<nodeBlocks, 256, 0, stream>>>(buf1, offs, srcs, dis, bs[l], buf0, N);
    }

    matmulAB_k<<<mmBlocks, 256, 0, stream>>>(buf0, Wm1, Wm1 + 128 * 128, buf1, buf2, N);

    edge_mlp_k<<<nodeBlocks, 256, 0, stream>>>(offs, srcs, eid, buf1, buf2, Wm2, bm1, bm2, out, N);
}

// Round 7
// 809.735 us; speedup vs baseline: 1.0548x; 1.0036x over previous
//
#include <hip/hip_runtime.h>
#include <hip/hip_bf16.h>

#define N_NODES 100000
#define N_EDGES 1600000

// ---------------- CSR build ----------------

__global__ void hist_k(const int* __restrict__ ei, int* __restrict__ cnt, int E) {
    int e = blockIdx.x * 256 + threadIdx.x;
    if (e < E) atomicAdd(&cnt[ei[E + e]], 1);
}

// scan + dis/sxp fused: reads cnt once, emits exclusive block-scan, dis, packed sxp
// sxp[i] = bits of dis[i] with low 4 mantissa bits holding x[i] (rel err <= 1.8e-6)
__global__ void scan_cnt_k(const int* __restrict__ cnt, const int* __restrict__ x,
                           int* __restrict__ offs, int* __restrict__ bsum,
                           float* __restrict__ dis, int* __restrict__ sxp, int n) {
    __shared__ int buf[2][256];
    int t = threadIdx.x;
    int i = blockIdx.x * 256 + t;
    int v = (i < n) ? cnt[i] : 0;
    if (i < n) {
        float d = rsqrtf(1.0f + (float)v);   // deg includes self-loop
        dis[i] = d;
        sxp[i] = (__float_as_int(d) & ~15) | x[i];
    }
    int p = 0;
    buf[0][t] = v;
    __syncthreads();
    for (int off = 1; off < 256; off <<= 1) {
        int nv = buf[p][t];
        if (t >= off) nv += buf[p][t - off];
        buf[p ^ 1][t] = nv;
        p ^= 1;
        __syncthreads();
    }
    if (i < n) offs[i] = buf[p][t] - v;
    if (t == 255) bsum[blockIdx.x] = buf[p][t];
}

__global__ void scan_bsum_k(int* __restrict__ bsum, int nb) {
    __shared__ int buf[2][512];
    int t = threadIdx.x;
    int v = (t < nb) ? bsum[t] : 0;
    int p = 0;
    buf[0][t] = v;
    __syncthreads();
    for (int off = 1; off < 512; off <<= 1) {
        int nv = buf[p][t];
        if (t >= off) nv += buf[p][t - off];
        buf[p ^ 1][t] = nv;
        p ^= 1;
        __syncthreads();
    }
    if (t < nb) bsum[t] = buf[p][t] - v;
}

__global__ void scan_add_k(int* __restrict__ offs, int* __restrict__ cursor,
                           const int* __restrict__ bsum, int n, int total) {
    int i = blockIdx.x * 256 + threadIdx.x;
    if (i < n) {
        int o = offs[i] + bsum[blockIdx.x];
        offs[i] = o;
        cursor[i] = o;
    }
    if (i == 0) offs[n] = total;
}

// bucketed by dst: srcs[pos] = src, eid[pos] = edge id
__global__ void fill_csr_k(const int* __restrict__ ei, int* __restrict__ cursor,
                           int* __restrict__ srcs, int* __restrict__ eid, int E) {
    int e = blockIdx.x * 256 + threadIdx.x;
    if (e < E) {
        int s = ei[e];
        int d = ei[E + e];
        int pos = atomicAdd(&cursor[d], 1);
        srcs[pos] = s;
        eid[pos] = e;
    }
}

// ---------------- layer 0+1 fused via vocab table ----------------

// T0[v][c] = sum_k emb[v][k] * W0[k][c]
__global__ void t0_k(const float* __restrict__ emb, const float* __restrict__ W0,
                     float* __restrict__ T0) {
    int v = blockIdx.x;      // 16 blocks
    int c = threadIdx.x;     // 128 threads
    float acc = 0.f;
    for (int k = 0; k < 128; ++k) acc += emb[v * 128 + k] * W0[k * 128 + c];
    T0[v * 128 + c] = acc;
}

// h1[d] = relu( di * (cvec @ T0) + b0 ),  cvec[v] = sum_{s: x[s]=v} dis[s] (+ di for self)
__global__ __launch_bounds__(256) void vgather_k(const int* __restrict__ sxp,
                                                 const int* __restrict__ offs,
                                                 const int* __restrict__ srcs,
                                                 const float* __restrict__ dis,
                                                 const float* __restrict__ T0,
                                                 const float* __restrict__ b0,
                                                 float* __restrict__ h, int n) {
    __shared__ float t0s[16 * 128];
    __shared__ float cv[4][16];
    int t = threadIdx.x;
    #pragma unroll
    for (int i = 0; i < 8; ++i) t0s[t + i * 256] = T0[t + i * 256];
    if (t < 64) cv[t >> 4][t & 15] = 0.f;
    __syncthreads();

    int w = t >> 6, lane = t & 63;
    int node = blockIdx.x * 4 + w;            // grid exact: N/4 blocks
    float di = dis[node];
    int j0 = offs[node], j1 = offs[node + 1];
    for (int j = j0 + lane; j < j1; j += 64) {
        int b = sxp[srcs[j]];                  // packed {dis[s], x[s]}
        atomicAdd(&cv[w][b & 15], __int_as_float(b));
    }
    if (lane == 0) atomicAdd(&cv[w][sxp[node] & 15], di);   // self loop
    __syncthreads();

    float2 acc = make_float2(0.f, 0.f);
    #pragma unroll
    for (int v = 0; v < 16; ++v) {
        float c = cv[w][v];
        float2 tv = *(const float2*)&t0s[v * 128 + lane * 2];
        acc.x += c * tv.x;
        acc.y += c * tv.y;
    }
    float2 bb = *(const float2*)&b0[lane * 2];
    float2 r = make_float2(fmaxf(di * acc.x + bb.x, 0.f),
                           fmaxf(di * acc.y + bb.y, 0.f));
    ((float2*)h)[(size_t)node * 64 + lane] = r;
}

// ---------------- node matmul (row-prescaled by dis) — round-3 proven form ----------------

__global__ __launch_bounds__(256) void matmul128_k(const float* __restrict__ in,
                                                   const float* __restrict__ W,
                                                   float* __restrict__ out,
                                                   const float* __restrict__ scale,
                                                   int n) {
    __shared__ float hlds[64][132];
    int t = threadIdx.x;
    int row0 = blockIdx.x * 64;
    #pragma unroll
    for (int it = 0; it < 8; ++it) {
        int i4 = t + it * 256;
        int r = i4 >> 5, c4 = (i4 & 31) << 2;
        float4 v = make_float4(0.f, 0.f, 0.f, 0.f);
        int g = row0 + r;
        if (g < n) v = *(const float4*)&in[(size_t)g * 128 + c4];
        *(float4*)&hlds[r][c4] = v;
    }
    __syncthreads();
    int cg = t & 31, rg = t >> 5;
    int c0 = cg << 2;
    float acc[8][4];
    #pragma unroll
    for (int r = 0; r < 8; ++r)
        for (int j = 0; j < 4; ++j) acc[r][j] = 0.f;
    #pragma unroll 4
    for (int k = 0; k < 128; ++k) {
        float4 w = *(const float4*)&W[(size_t)k * 128 + c0];
        #pragma unroll
        for (int r = 0; r < 8; ++r) {
            float hk = hlds[rg * 8 + r][k];
            acc[r][0] += hk * w.x;
            acc[r][1] += hk * w.y;
            acc[r][2] += hk * w.z;
            acc[r][3] += hk * w.w;
        }
    }
    #pragma unroll
    for (int r = 0; r < 8; ++r) {
        int g = row0 + rg * 8 + r;
        if (g < n) {
            float sc = scale[g];
            float4 o = make_float4(acc[r][0] * sc, acc[r][1] * sc,
                                   acc[r][2] * sc, acc[r][3] * sc);
            *(float4*)&out[(size_t)g * 128 + c0] = o;
        }
    }
}

// ---------------- fused gather + matmul ----------------
// Phase 1: 8 groups x 8 lanes per wave gather 16 nodes/wave (64/block) into LDS
//          (identical body to the proven gcn_gather_k, destination = LDS tile).
// Phase 2: proven matmul128 body, staging elided (tile already in LDS).

__device__ __forceinline__ void gather_tile_to_lds(
    const float4* __restrict__ hw4, const int* __restrict__ offs,
    const int* __restrict__ srcs, const float* __restrict__ dis,
    const float* __restrict__ bias, float hlds[64][132],
    int row0, int n, int t) {
    int w = t >> 6, lane = t & 63;
    int g = lane >> 3, sl = lane & 7;
    float4 bb[4];
    #pragma unroll
    for (int k = 0; k < 4; ++k) bb[k] = ((const float4*)bias)[sl + 8 * k];
    for (int i = 0; i < 16; ++i) {
        int nl = (w << 4) + i;
        int node = row0 + nl;
        if (node >= n) break;                 // uniform across wave
        size_t selfrb = (size_t)node * 32 + sl;
        float4 a[4];
        if (g == 0) {
            #pragma unroll
            for (int k = 0; k < 4; ++k) a[k] = hw4[selfrb + 8 * k];
        } else {
            #pragma unroll
            for (int k = 0; k < 4; ++k) a[k] = make_float4(0.f, 0.f, 0.f, 0.f);
        }
        int j0 = offs[node], j1 = offs[node + 1];
        for (int j = j0 + g; j < j1; j += 8) {
            size_t rb = (size_t)srcs[j] * 32 + sl;
            #pragma unroll
            for (int k = 0; k < 4; ++k) {
                float4 u = hw4[rb + 8 * k];
                a[k].x += u.x; a[k].y += u.y; a[k].z += u.z; a[k].w += u.w;
            }
        }
        #pragma unroll
        for (int m = 8; m <= 32; m <<= 1) {
            #pragma unroll
            for (int k = 0; k < 4; ++k) {
                a[k].x += __shfl_xor(a[k].x, m);
                a[k].y += __shfl_xor(a[k].y, m);
                a[k].z += __shfl_xor(a[k].z, m);
                a[k].w += __shfl_xor(a[k].w, m);
            }
        }
        if (g == 0) {
            float di = dis[node];
            #pragma unroll
            for (int k = 0; k < 4; ++k) {
                float4 r = make_float4(fmaxf(di * a[k].x + bb[k].x, 0.f),
                                       fmaxf(di * a[k].y + bb[k].y, 0.f),
                                       fmaxf(di * a[k].z + bb[k].z, 0.f),
                                       fmaxf(di * a[k].w + bb[k].w, 0.f));
                *(float4*)&hlds[nl][(sl + 8 * k) * 4] = r;
            }
        }
    }
}

// fused: h_{l+1} tile = gather(hWin), out = (h_{l+1} @ W) * dis[row]
__global__ __launch_bounds__(256) void fused_gm_k(
    const float* __restrict__ hWin, const int* __restrict__ offs,
    const int* __restrict__ srcs, const float* __restrict__ dis,
    const float* __restrict__ bias, const float* __restrict__ W,
    float* __restrict__ out, int n) {
    __shared__ float hlds[64][132];
    int t = threadIdx.x;
    int row0 = blockIdx.x * 64;
    gather_tile_to_lds((const float4*)hWin, offs, srcs, dis, bias, hlds, row0, n, t);
    __syncthreads();
    int cg = t & 31, rg = t >> 5;
    int c0 = cg << 2;
    float acc[8][4];
    #pragma unroll
    for (int r = 0; r < 8; ++r)
        for (int j = 0; j < 4; ++j) acc[r][j] = 0.f;
    #pragma unroll 4
    for (int k = 0; k < 128; ++k) {
        float4 w = *(const float4*)&W[(size_t)k * 128 + c0];
        #pragma unroll
        for (int r = 0; r < 8; ++r) {
            float hk = hlds[rg * 8 + r][k];
            acc[r][0] += hk * w.x;
            acc[r][1] += hk * w.y;
            acc[r][2] += hk * w.z;
            acc[r][3] += hk * w.w;
        }
    }
    #pragma unroll
    for (int r = 0; r < 8; ++r) {
        int gr = row0 + rg * 8 + r;
        if (gr < n) {
            float sc = dis[gr];
            float4 o = make_float4(acc[r][0] * sc, acc[r][1] * sc,
                                   acc[r][2] * sc, acc[r][3] * sc);
            *(float4*)&out[(size_t)gr * 128 + c0] = o;
        }
    }
}

// fused dual: h3 tile = gather(hWin), A = h3 @ WA, B = h3 @ WB (unscaled)
__global__ __launch_bounds__(256) void fused_gm2_k(
    const float* __restrict__ hWin, const int* __restrict__ offs,
    const int* __restrict__ srcs, const float* __restrict__ dis,
    const float* __restrict__ bias, const float* __restrict__ WA,
    const float* __restrict__ WB, float* __restrict__ outA,
    float* __restrict__ outB, int n) {
    __shared__ float hlds[64][132];
    int t = threadIdx.x;
    int row0 = blockIdx.x * 64;
    gather_tile_to_lds((const float4*)hWin, offs, srcs, dis, bias, hlds, row0, n, t);
    __syncthreads();
    int cg = t & 31, rg = t >> 5;
    int c0 = cg << 2;
    float accA[8][4], accB[8][4];
    #pragma unroll
    for (int r = 0; r < 8; ++r)
        for (int j = 0; j < 4; ++j) { accA[r][j] = 0.f; accB[r][j] = 0.f; }
    #pragma unroll 2
    for (int k = 0; k < 128; ++k) {
        float4 wa = *(const float4*)&WA[(size_t)k * 128 + c0];
        float4 wb = *(const float4*)&WB[(size_t)k * 128 + c0];
        #pragma unroll
        for (int r = 0; r < 8; ++r) {
            float hk = hlds[rg * 8 + r][k];
            accA[r][0] += hk * wa.x;
            accA[r][1] += hk * wa.y;
            accA[r][2] += hk * wa.z;
            accA[r][3] += hk * wa.w;
            accB[r][0] += hk * wb.x;
            accB[r][1] += hk * wb.y;
            accB[r][2] += hk * wb.z;
            accB[r][3] += hk * wb.w;
        }
    }
    #pragma unroll
    for (int r = 0; r < 8; ++r) {
        int gr = row0 + rg * 8 + r;
        if (gr < n) {
            *(float4*)&outA[(size_t)gr * 128 + c0] = *(float4*)&accA[r][0];
            *(float4*)&outB[(size_t)gr * 128 + c0] = *(float4*)&accB[r][0];
        }
    }
}

// ---------------- edge MLP: CSR by dst, 4 edges x 16 lanes per wave ----------------
// (round-3 proven form: VGPR ~32, occupancy ~77%)
__global__ __launch_bounds__(256) void edge_mlp_k(const int* __restrict__ offs,
                                                  const int* __restrict__ srcs,
                                                  const int* __restrict__ eid,
                                                  const float* __restrict__ A,
                                                  const float* __restrict__ B,
                                                  const float* __restrict__ Wm2,
                                                  const float* __restrict__ bm1,
                                                  const float* __restrict__ bm2,
                                                  float* __restrict__ out, int n) {
    int t = threadIdx.x;
    int node = blockIdx.x * 4 + (t >> 6);
    int lane = t & 63;
    int g = lane >> 4, sl = lane & 15;
    int j0 = offs[node], j1 = offs[node + 1];
    if (j0 == j1) return;

    // pre = B[node][sl*8 .. +8] + bm1
    const float4* B4 = (const float4*)(B + (size_t)node * 128 + sl * 8);
    const float4* bm14 = (const float4*)(bm1 + sl * 8);
    float4 pre0 = B4[0], pre1 = B4[1];
    float4 m0 = bm14[0], m1 = bm14[1];
    pre0.x += m0.x; pre0.y += m0.y; pre0.z += m0.z; pre0.w += m0.w;
    pre1.x += m1.x; pre1.y += m1.y; pre1.z += m1.z; pre1.w += m1.w;

    float wv[8][3];
    #pragma unroll
    for (int i = 0; i < 8; ++i) {
        int f = sl * 8 + i;
        wv[i][0] = Wm2[f * 3 + 0];
        wv[i][1] = Wm2[f * 3 + 1];
        wv[i][2] = Wm2[f * 3 + 2];
    }
    float c0 = bm2[0], c1 = bm2[1], c2 = bm2[2];

    for (int jb = j0; jb < j1; jb += 4) {
        int jj = jb + g;
        bool act = jj < j1;
        int jsafe = act ? jj : j0;
        int s = srcs[jsafe];
        int e = eid[jsafe];
        const float4* A4 = (const float4*)(A + (size_t)s * 128 + sl * 8);
        float4 a0 = A4[0], a1 = A4[1];
        float h[8];
        h[0] = fmaxf(a0.x + pre0.x, 0.f);
        h[1] = fmaxf(a0.y + pre0.y, 0.f);
        h[2] = fmaxf(a0.z + pre0.z, 0.f);
        h[3] = fmaxf(a0.w + pre0.w, 0.f);
        h[4] = fmaxf(a1.x + pre1.x, 0.f);
        h[5] = fmaxf(a1.y + pre1.y, 0.f);
        h[6] = fmaxf(a1.z + pre1.z, 0.f);
        h[7] = fmaxf(a1.w + pre1.w, 0.f);
        float p0 = 0.f, p1 = 0.f, p2 = 0.f;
        #pragma unroll
        for (int i = 0; i < 8; ++i) {
            p0 += h[i] * wv[i][0];
            p1 += h[i] * wv[i][1];
            p2 += h[i] * wv[i][2];
        }
        #pragma unroll
        for (int m = 1; m <= 8; m <<= 1) {
            p0 += __shfl_xor(p0, m);
            p1 += __shfl_xor(p1, m);
            p2 += __shfl_xor(p2, m);
        }
        if (act && sl == 0) {
            out[(size_t)e * 3 + 0] = p0 + c0;
            out[(size_t)e * 3 + 1] = p1 + c1;
            out[(size_t)e * 3 + 2] = p2 + c2;
        }
    }
}

extern "C" void kernel_launch(void* const* d_in, const int* in_sizes, int n_in,
                              void* d_out, int out_size, void* d_ws, size_t ws_size,
                              hipStream_t stream) {
    const int N = N_NODES, E = N_EDGES;
    const int* x    = (const int*)d_in[0];
    const int* ei   = (const int*)d_in[1];
    const float* emb = (const float*)d_in[2];
    const float* W0 = (const float*)d_in[3];
    const float* b0 = (const float*)d_in[4];
    const float* W1 = (const float*)d_in[5];
    const float* b1 = (const float*)d_in[6];
    const float* W2 = (const float*)d_in[7];
    const float* b2 = (const float*)d_in[8];
    const float* Wm1 = (const float*)d_in[9];
    const float* bm1 = (const float*)d_in[10];
    const float* Wm2 = (const float*)d_in[11];
    const float* bm2 = (const float*)d_in[12];
    float* out = (float*)d_out;

    char* p = (char*)d_ws;
    auto alloc = [&](size_t bytes) {
        char* r = p;
        p += (bytes + 511) & ~(size_t)511;
        return r;
    };
    int*    cnt    = (int*)alloc((size_t)N * 4);
    float*  dis    = (float*)alloc((size_t)N * 4);
    int*    sxp    = (int*)alloc((size_t)N * 4);
    int*    offs   = (int*)alloc((size_t)(N + 1) * 4);
    int*    cursor = (int*)alloc((size_t)N * 4);
    int*    bsum   = (int*)alloc(512 * 4);
    int*    srcs   = (int*)alloc((size_t)E * 4);
    int*    eid    = (int*)alloc((size_t)E * 4);
    float*  T0     = (float*)alloc(16 * 128 * 4);
    float*  buf0   = (float*)alloc((size_t)N * 128 * 4);
    float*  buf1   = (float*)alloc((size_t)N * 128 * 4);
    float*  buf2   = (float*)alloc((size_t)N * 128 * 4);

    int nbN = (N + 255) / 256;
    int nbE = (E + 255) / 256;
    int nodeBlocks = N / 4;               // N divisible by 4
    int mmBlocks = (N + 63) / 64;

    hipMemsetAsync(cnt, 0, (size_t)N * 4, stream);
    hist_k<<<nbE, 256, 0, stream>>>(ei, cnt, E);
    scan_cnt_k<<<nbN, 256, 0, stream>>>(cnt, x, offs, bsum, dis, sxp, N);
    scan_bsum_k<<<1, 512, 0, stream>>>(bsum, nbN);
    scan_add_k<<<nbN, 256, 0, stream>>>(offs, cursor, bsum, N, E);
    fill_csr_k<<<nbE, 256, 0, stream>>>(ei, cursor, srcs, eid, E);

    t0_k<<<16, 128, 0, stream>>>(emb, W0, T0);
    vgather_k<<<nodeBlocks, 256, 0, stream>>>(sxp, offs, srcs, dis, T0, b0, buf0, N);

    // h1 @ W1 (dis-prescaled) -> buf1
    matmul128_k<<<mmBlocks, 256, 0, stream>>>(buf0, W1, buf1, dis, N);
    // gather(buf1)+b1 -> h2 tile; h2 @ W2 (dis-prescaled) -> buf0
    fused_gm_k<<<mmBlocks, 256, 0, stream>>>(buf1, offs, srcs, dis, b1, W2, buf0, N);
    // gather(buf0)+b2 -> h3 tile; h3 @ Wm1A -> buf1, h3 @ Wm1B -> buf2
    fused_gm2_k<<<mmBlocks, 256, 0, stream>>>(buf0, offs, srcs, dis, b2,
                                              Wm1, Wm1 + 128 * 128, buf1, buf2, N);

    edge_mlp_k<<<nodeBlocks, 256, 0, stream>>>(offs, srcs, eid, buf1, buf2, Wm2, bm1, bm2, out, N);
}

// Round 8
// 806.865 us; speedup vs baseline: 1.0585x; 1.0036x over previous
//
#include <hip/hip_runtime.h>
#include <hip/hip_bf16.h>

#define N_NODES 100000
#define N_EDGES 1600000

// ---------------- CSR build ----------------

__global__ void hist_k(const int* __restrict__ ei, int* __restrict__ cnt, int E) {
    int e = blockIdx.x * 256 + threadIdx.x;
    if (e < E) atomicAdd(&cnt[ei[E + e]], 1);
}

// scan + dis/sxp fused: reads cnt once, emits exclusive block-scan, dis, packed sxp
// sxp[i] = bits of dis[i] with low 4 mantissa bits holding x[i] (rel err <= 1.8e-6)
__global__ void scan_cnt_k(const int* __restrict__ cnt, const int* __restrict__ x,
                           int* __restrict__ offs, int* __restrict__ bsum,
                           float* __restrict__ dis, int* __restrict__ sxp, int n) {
    __shared__ int buf[2][256];
    int t = threadIdx.x;
    int i = blockIdx.x * 256 + t;
    int v = (i < n) ? cnt[i] : 0;
    if (i < n) {
        float d = rsqrtf(1.0f + (float)v);   // deg includes self-loop
        dis[i] = d;
        sxp[i] = (__float_as_int(d) & ~15) | x[i];
    }
    int p = 0;
    buf[0][t] = v;
    __syncthreads();
    for (int off = 1; off < 256; off <<= 1) {
        int nv = buf[p][t];
        if (t >= off) nv += buf[p][t - off];
        buf[p ^ 1][t] = nv;
        p ^= 1;
        __syncthreads();
    }
    if (i < n) offs[i] = buf[p][t] - v;
    if (t == 255) bsum[blockIdx.x] = buf[p][t];
}

__global__ void scan_bsum_k(int* __restrict__ bsum, int nb) {
    __shared__ int buf[2][512];
    int t = threadIdx.x;
    int v = (t < nb) ? bsum[t] : 0;
    int p = 0;
    buf[0][t] = v;
    __syncthreads();
    for (int off = 1; off < 512; off <<= 1) {
        int nv = buf[p][t];
        if (t >= off) nv += buf[p][t - off];
        buf[p ^ 1][t] = nv;
        p ^= 1;
        __syncthreads();
    }
    if (t < nb) bsum[t] = buf[p][t] - v;
}

__global__ void scan_add_k(int* __restrict__ offs, int* __restrict__ cursor,
                           const int* __restrict__ bsum, int n, int total) {
    int i = blockIdx.x * 256 + threadIdx.x;
    if (i < n) {
        int o = offs[i] + bsum[blockIdx.x];
        offs[i] = o;
        cursor[i] = o;
    }
    if (i == 0) offs[n] = total;
}

// bucketed by dst: srcs[pos] = src, eid[pos] = edge id
__global__ void fill_csr_k(const int* __restrict__ ei, int* __restrict__ cursor,
                           int* __restrict__ srcs, int* __restrict__ eid, int E) {
    int e = blockIdx.x * 256 + threadIdx.x;
    if (e < E) {
        int s = ei[e];
        int d = ei[E + e];
        int pos = atomicAdd(&cursor[d], 1);
        srcs[pos] = s;
        eid[pos] = e;
    }
}

// ---------------- layer 0+1 fused via vocab table ----------------

// T0[v][c] = sum_k emb[v][k] * W0[k][c]
__global__ void t0_k(const float* __restrict__ emb, const float* __restrict__ W0,
                     float* __restrict__ T0) {
    int v = blockIdx.x;      // 16 blocks
    int c = threadIdx.x;     // 128 threads
    float acc = 0.f;
    for (int k = 0; k < 128; ++k) acc += emb[v * 128 + k] * W0[k * 128 + c];
    T0[v * 128 + c] = acc;
}

// h1[d] = relu( di * (cvec @ T0) + b0 ),  cvec[v] = sum_{s: x[s]=v} dis[s] (+ di for self)
__global__ __launch_bounds__(256) void vgather_k(const int* __restrict__ sxp,
                                                 const int* __restrict__ offs,
                                                 const int* __restrict__ srcs,
                                                 const float* __restrict__ dis,
                                                 const float* __restrict__ T0,
                                                 const float* __restrict__ b0,
                                                 float* __restrict__ h, int n) {
    __shared__ float t0s[16 * 128];
    __shared__ float cv[4][16];
    int t = threadIdx.x;
    #pragma unroll
    for (int i = 0; i < 8; ++i) t0s[t + i * 256] = T0[t + i * 256];
    if (t < 64) cv[t >> 4][t & 15] = 0.f;
    __syncthreads();

    int w = t >> 6, lane = t & 63;
    int node = blockIdx.x * 4 + w;            // grid exact: N/4 blocks
    float di = dis[node];
    int j0 = offs[node], j1 = offs[node + 1];
    for (int j = j0 + lane; j < j1; j += 64) {
        int b = sxp[srcs[j]];                  // packed {dis[s], x[s]}
        atomicAdd(&cv[w][b & 15], __int_as_float(b));
    }
    if (lane == 0) atomicAdd(&cv[w][sxp[node] & 15], di);   // self loop
    __syncthreads();

    float2 acc = make_float2(0.f, 0.f);
    #pragma unroll
    for (int v = 0; v < 16; ++v) {
        float c = cv[w][v];
        float2 tv = *(const float2*)&t0s[v * 128 + lane * 2];
        acc.x += c * tv.x;
        acc.y += c * tv.y;
    }
    float2 bb = *(const float2*)&b0[lane * 2];
    float2 r = make_float2(fmaxf(di * acc.x + bb.x, 0.f),
                           fmaxf(di * acc.y + bb.y, 0.f));
    ((float2*)h)[(size_t)node * 64 + lane] = r;
}

// ---------------- node matmul (row-prescaled by dis) — round-3 proven form ----------------
// LDS tile [64][128]: phase-2 reads are same-address broadcasts (no conflicts),
// staging writes are 512B-contiguous per wave -> padding unnecessary.
// 32768 B/block = exactly 5 blocks/CU.

__global__ __launch_bounds__(256) void matmul128_k(const float* __restrict__ in,
                                                   const float* __restrict__ W,
                                                   float* __restrict__ out,
                                                   const float* __restrict__ scale,
                                                   int n) {
    __shared__ float hlds[64][128];
    int t = threadIdx.x;
    int row0 = blockIdx.x * 64;
    #pragma unroll
    for (int it = 0; it < 8; ++it) {
        int i4 = t + it * 256;
        int r = i4 >> 5, c4 = (i4 & 31) << 2;
        float4 v = make_float4(0.f, 0.f, 0.f, 0.f);
        int g = row0 + r;
        if (g < n) v = *(const float4*)&in[(size_t)g * 128 + c4];
        *(float4*)&hlds[r][c4] = v;
    }
    __syncthreads();
    int cg = t & 31, rg = t >> 5;
    int c0 = cg << 2;
    float acc[8][4];
    #pragma unroll
    for (int r = 0; r < 8; ++r)
        for (int j = 0; j < 4; ++j) acc[r][j] = 0.f;
    #pragma unroll 4
    for (int k = 0; k < 128; ++k) {
        float4 w = *(const float4*)&W[(size_t)k * 128 + c0];
        #pragma unroll
        for (int r = 0; r < 8; ++r) {
            float hk = hlds[rg * 8 + r][k];
            acc[r][0] += hk * w.x;
            acc[r][1] += hk * w.y;
            acc[r][2] += hk * w.z;
            acc[r][3] += hk * w.w;
        }
    }
    #pragma unroll
    for (int r = 0; r < 8; ++r) {
        int g = row0 + rg * 8 + r;
        if (g < n) {
            float sc = scale[g];
            float4 o = make_float4(acc[r][0] * sc, acc[r][1] * sc,
                                   acc[r][2] * sc, acc[r][3] * sc);
            *(float4*)&out[(size_t)g * 128 + c0] = o;
        }
    }
}

// ---------------- fused gather + matmul ----------------
// Phase 1: 8 groups x 8 lanes per wave gather 16 nodes/wave (64/block) into LDS
// Phase 2: proven matmul128 body, staging elided (tile already in LDS).

__device__ __forceinline__ void gather_tile_to_lds(
    const float4* __restrict__ hw4, const int* __restrict__ offs,
    const int* __restrict__ srcs, const float* __restrict__ dis,
    const float* __restrict__ bias, float hlds[64][128],
    int row0, int n, int t) {
    int w = t >> 6, lane = t & 63;
    int g = lane >> 3, sl = lane & 7;
    float4 bb[4];
    #pragma unroll
    for (int k = 0; k < 4; ++k) bb[k] = ((const float4*)bias)[sl + 8 * k];
    for (int i = 0; i < 16; ++i) {
        int nl = (w << 4) + i;
        int node = row0 + nl;
        if (node >= n) break;                 // uniform across wave
        size_t selfrb = (size_t)node * 32 + sl;
        float4 a[4];
        if (g == 0) {
            #pragma unroll
            for (int k = 0; k < 4; ++k) a[k] = hw4[selfrb + 8 * k];
        } else {
            #pragma unroll
            for (int k = 0; k < 4; ++k) a[k] = make_float4(0.f, 0.f, 0.f, 0.f);
        }
        int j0 = offs[node], j1 = offs[node + 1];
        for (int j = j0 + g; j < j1; j += 8) {
            size_t rb = (size_t)srcs[j] * 32 + sl;
            #pragma unroll
            for (int k = 0; k < 4; ++k) {
                float4 u = hw4[rb + 8 * k];
                a[k].x += u.x; a[k].y += u.y; a[k].z += u.z; a[k].w += u.w;
            }
        }
        #pragma unroll
        for (int m = 8; m <= 32; m <<= 1) {
            #pragma unroll
            for (int k = 0; k < 4; ++k) {
                a[k].x += __shfl_xor(a[k].x, m);
                a[k].y += __shfl_xor(a[k].y, m);
                a[k].z += __shfl_xor(a[k].z, m);
                a[k].w += __shfl_xor(a[k].w, m);
            }
        }
        if (g == 0) {
            float di = dis[node];
            #pragma unroll
            for (int k = 0; k < 4; ++k) {
                float4 r = make_float4(fmaxf(di * a[k].x + bb[k].x, 0.f),
                                       fmaxf(di * a[k].y + bb[k].y, 0.f),
                                       fmaxf(di * a[k].z + bb[k].z, 0.f),
                                       fmaxf(di * a[k].w + bb[k].w, 0.f));
                *(float4*)&hlds[nl][(sl + 8 * k) * 4] = r;
            }
        }
    }
}

// fused: h_{l+1} tile = gather(hWin), out = (h_{l+1} @ W) * dis[row]
__global__ __launch_bounds__(256) void fused_gm_k(
    const float* __restrict__ hWin, const int* __restrict__ offs,
    const int* __restrict__ srcs, const float* __restrict__ dis,
    const float* __restrict__ bias, const float* __restrict__ W,
    float* __restrict__ out, int n) {
    __shared__ float hlds[64][128];
    int t = threadIdx.x;
    int row0 = blockIdx.x * 64;
    gather_tile_to_lds((const float4*)hWin, offs, srcs, dis, bias, hlds, row0, n, t);
    __syncthreads();
    int cg = t & 31, rg = t >> 5;
    int c0 = cg << 2;
    float acc[8][4];
    #pragma unroll
    for (int r = 0; r < 8; ++r)
        for (int j = 0; j < 4; ++j) acc[r][j] = 0.f;
    #pragma unroll 4
    for (int k = 0; k < 128; ++k) {
        float4 w = *(const float4*)&W[(size_t)k * 128 + c0];
        #pragma unroll
        for (int r = 0; r < 8; ++r) {
            float hk = hlds[rg * 8 + r][k];
            acc[r][0] += hk * w.x;
            acc[r][1] += hk * w.y;
            acc[r][2] += hk * w.z;
            acc[r][3] += hk * w.w;
        }
    }
    #pragma unroll
    for (int r = 0; r < 8; ++r) {
        int gr = row0 + rg * 8 + r;
        if (gr < n) {
            float sc = dis[gr];
            float4 o = make_float4(acc[r][0] * sc, acc[r][1] * sc,
                                   acc[r][2] * sc, acc[r][3] * sc);
            *(float4*)&out[(size_t)gr * 128 + c0] = o;
        }
    }
}

// fused dual: h3 tile = gather(hWin), A = h3 @ WA, B = h3 @ WB (unscaled)
__global__ __launch_bounds__(256) void fused_gm2_k(
    const float* __restrict__ hWin, const int* __restrict__ offs,
    const int* __restrict__ srcs, const float* __restrict__ dis,
    const float* __restrict__ bias, const float* __restrict__ WA,
    const float* __restrict__ WB, float* __restrict__ outA,
    float* __restrict__ outB, int n) {
    __shared__ float hlds[64][128];
    int t = threadIdx.x;
    int row0 = blockIdx.x * 64;
    gather_tile_to_lds((const float4*)hWin, offs, srcs, dis, bias, hlds, row0, n, t);
    __syncthreads();
    int cg = t & 31, rg = t >> 5;
    int c0 = cg << 2;
    float accA[8][4], accB[8][4];
    #pragma unroll
    for (int r = 0; r < 8; ++r)
        for (int j = 0; j < 4; ++j) { accA[r][j] = 0.f; accB[r][j] = 0.f; }
    #pragma unroll 2
    for (int k = 0; k < 128; ++k) {
        float4 wa = *(const float4*)&WA[(size_t)k * 128 + c0];
        float4 wb = *(const float4*)&WB[(size_t)k * 128 + c0];
        #pragma unroll
        for (int r = 0; r < 8; ++r) {
            float hk = hlds[rg * 8 + r][k];
            accA[r][0] += hk * wa.x;
            accA[r][1] += hk * wa.y;
            accA[r][2] += hk * wa.z;
            accA[r][3] += hk * wa.w;
            accB[r][0] += hk * wb.x;
            accB[r][1] += hk * wb.y;
            accB[r][2] += hk * wb.z;
            accB[r][3] += hk * wb.w;
        }
    }
    #pragma unroll
    for (int r = 0; r < 8; ++r) {
        int gr = row0 + rg * 8 + r;
        if (gr < n) {
            *(float4*)&outA[(size_t)gr * 128 + c0] = *(float4*)&accA[r][0];
            *(float4*)&outB[(size_t)gr * 128 + c0] = *(float4*)&accB[r][0];
        }
    }
}

// ---------------- edge MLP: CSR by dst, 4 edges x 16 lanes per wave ----------------
// (round-3 proven form: VGPR ~32, occupancy ~77%)
__global__ __launch_bounds__(256) void edge_mlp_k(const int* __restrict__ offs,
                                                  const int* __restrict__ srcs,
                                                  const int* __restrict__ eid,
                                                  const float* __restrict__ A,
                                                  const float* __restrict__ B,
                                                  const float* __restrict__ Wm2,
                                                  const float* __restrict__ bm1,
                                                  const float* __restrict__ bm2,
                                                  float* __restrict__ out, int n) {
    int t = threadIdx.x;
    int node = blockIdx.x * 4 + (t >> 6);
    int lane = t & 63;
    int g = lane >> 4, sl = lane & 15;
    int j0 = offs[node], j1 = offs[node + 1];
    if (j0 == j1) return;

    // pre = B[node][sl*8 .. +8] + bm1
    const float4* B4 = (const float4*)(B + (size_t)node * 128 + sl * 8);
    const float4* bm14 = (const float4*)(bm1 + sl * 8);
    float4 pre0 = B4[0], pre1 = B4[1];
    float4 m0 = bm14[0], m1 = bm14[1];
    pre0.x += m0.x; pre0.y += m0.y; pre0.z += m0.z; pre0.w += m0.w;
    pre1.x += m1.x; pre1.y += m1.y; pre1.z += m1.z; pre1.w += m1.w;

    float wv[8][3];
    #pragma unroll
    for (int i = 0; i < 8; ++i) {
        int f = sl * 8 + i;
        wv[i][0] = Wm2[f * 3 + 0];
        wv[i][1] = Wm2[f * 3 + 1];
        wv[i][2] = Wm2[f * 3 + 2];
    }
    float c0 = bm2[0], c1 = bm2[1], c2 = bm2[2];

    for (int jb = j0; jb < j1; jb += 4) {
        int jj = jb + g;
        bool act = jj < j1;
        int jsafe = act ? jj : j0;
        int s = srcs[jsafe];
        int e = eid[jsafe];
        const float4* A4 = (const float4*)(A + (size_t)s * 128 + sl * 8);
        float4 a0 = A4[0], a1 = A4[1];
        float h[8];
        h[0] = fmaxf(a0.x + pre0.x, 0.f);
        h[1] = fmaxf(a0.y + pre0.y, 0.f);
        h[2] = fmaxf(a0.z + pre0.z, 0.f);
        h[3] = fmaxf(a0.w + pre0.w, 0.f);
        h[4] = fmaxf(a1.x + pre1.x, 0.f);
        h[5] = fmaxf(a1.y + pre1.y, 0.f);
        h[6] = fmaxf(a1.z + pre1.z, 0.f);
        h[7] = fmaxf(a1.w + pre1.w, 0.f);
        float p0 = 0.f, p1 = 0.f, p2 = 0.f;
        #pragma unroll
        for (int i = 0; i < 8; ++i) {
            p0 += h[i] * wv[i][0];
            p1 += h[i] * wv[i][1];
            p2 += h[i] * wv[i][2];
        }
        #pragma unroll
        for (int m = 1; m <= 8; m <<= 1) {
            p0 += __shfl_xor(p0, m);
            p1 += __shfl_xor(p1, m);
            p2 += __shfl_xor(p2, m);
        }
        if (act && sl == 0) {
            out[(size_t)e * 3 + 0] = p0 + c0;
            out[(size_t)e * 3 + 1] = p1 + c1;
            out[(size_t)e * 3 + 2] = p2 + c2;
        }
    }
}

extern "C" void kernel_launch(void* const* d_in, const int* in_sizes, int n_in,
                              void* d_out, int out_size, void* d_ws, size_t ws_size,
                              hipStream_t stream) {
    const int N = N_NODES, E = N_EDGES;
    const int* x    = (const int*)d_in[0];
    const int* ei   = (const int*)d_in[1];
    const float* emb = (const float*)d_in[2];
    const float* W0 = (const float*)d_in[3];
    const float* b0 = (const float*)d_in[4];
    const float* W1 = (const float*)d_in[5];
    const float* b1 = (const float*)d_in[6];
    const float* W2 = (const float*)d_in[7];
    const float* b2 = (const float*)d_in[8];
    const float* Wm1 = (const float*)d_in[9];
    const float* bm1 = (const float*)d_in[10];
    const float* Wm2 = (const float*)d_in[11];
    const float* bm2 = (const float*)d_in[12];
    float* out = (float*)d_out;

    char* p = (char*)d_ws;
    auto alloc = [&](size_t bytes) {
        char* r = p;
        p += (bytes + 511) & ~(size_t)511;
        return r;
    };
    int*    cnt    = (int*)alloc((size_t)N * 4);
    float*  dis    = (float*)alloc((size_t)N * 4);
    int*    sxp    = (int*)alloc((size_t)N * 4);
    int*    offs   = (int*)alloc((size_t)(N + 1) * 4);
    int*    cursor = (int*)alloc((size_t)N * 4);
    int*    bsum   = (int*)alloc(512 * 4);
    int*    srcs   = (int*)alloc((size_t)E * 4);
    int*    eid    = (int*)alloc((size_t)E * 4);
    float*  T0     = (float*)alloc(16 * 128 * 4);
    float*  buf0   = (float*)alloc((size_t)N * 128 * 4);
    float*  buf1   = (float*)alloc((size_t)N * 128 * 4);
    float*  buf2   = (float*)alloc((size_t)N * 128 * 4);

    int nbN = (N + 255) / 256;
    int nbE = (E + 255) / 256;
    int nodeBlocks = N / 4;               // N divisible by 4
    int mmBlocks = (N + 63) / 64;

    hipMemsetAsync(cnt, 0, (size_t)N * 4, stream);
    hist_k<<<nbE, 256, 0, stream>>>(ei, cnt, E);
    scan_cnt_k<<<nbN, 256, 0, stream>>>(cnt, x, offs, bsum, dis, sxp, N);
    scan_bsum_k<<<1, 512, 0, stream>>>(bsum, nbN);
    scan_add_k<<<nbN, 256, 0, stream>>>(offs, cursor, bsum, N, E);
    fill_csr_k<<<nbE, 256, 0, stream>>>(ei, cursor, srcs, eid, E);

    t0_k<<<16, 128, 0, stream>>>(emb, W0, T0);
    vgather_k<<<nodeBlocks, 256, 0, stream>>>(sxp, offs, srcs, dis, T0, b0, buf0, N);

    // h1 @ W1 (dis-prescaled) -> buf1
    matmul128_k<<<mmBlocks, 256, 0, stream>>>(buf0, W1, buf1, dis, N);
    // gather(buf1)+b1 -> h2 tile; h2 @ W2 (dis-prescaled) -> buf0
    fused_gm_k<<<mmBlocks, 256, 0, stream>>>(buf1, offs, srcs, dis, b1, W2, buf0, N);
    // gather(buf0)+b2 -> h3 tile; h3 @ Wm1A -> buf1, h3 @ Wm1B -> buf2
    fused_gm2_k<<<mmBlocks, 256, 0, stream>>>(buf0, offs, srcs, dis, b2,
                                              Wm1, Wm1 + 128 * 128, buf1, buf2, N);

    edge_mlp_k<<<nodeBlocks, 256, 0, stream>>>(offs, srcs, eid, buf1, buf2, Wm2, bm1, bm2, out, N);
}